// Round 5
// baseline (840.439 us; speedup 1.0000x reference)
//
#include <hip/hip_runtime.h>
#include <math.h>

// Residual VQ: x[B,D] fp32, codebooks[L,K,D] fp32
// Outputs (flat concat, fp32): hard_indices[B,L], soft_probs[B,K,L],
//                              quantized[B,D], quant_losses[B,L]
#define Bq 65536
#define Dd 128
#define Kk 256
#define Ll 4

constexpr int BR = 64;        // rows per block
constexpr int THREADS = 256;  // 32 tx (codes) x 8 ty (rows)
constexpr int DC = 16;        // D-chunk staged in LDS

constexpr size_t OUT_IDX   = 0;
constexpr size_t OUT_PROBS = (size_t)Bq * Ll;                 // 262144
constexpr size_t OUT_QUANT = OUT_PROBS + (size_t)Bq * Kk * Ll; // 67371008
constexpr size_t OUT_LOSS  = OUT_QUANT + (size_t)Bq * Dd;      // 75759616

// cc[l*K+k] = sum_d cb[l][k][d]^2  (1024 values)
__global__ void cc_kernel(const float* __restrict__ cb, float* __restrict__ cc) {
  int k = blockIdx.x * blockDim.x + threadIdx.x;  // 0..1023
  const float4* row = (const float4*)(cb + (size_t)k * Dd);
  float s = 0.f;
#pragma unroll
  for (int i = 0; i < Dd / 4; ++i) {
    float4 v = row[i];
    s += v.x * v.x + v.y * v.y + v.z * v.z + v.w * v.w;
  }
  cc[k] = s;
}

__launch_bounds__(THREADS)
__global__ void rvq_kernel(const float* __restrict__ x, const float* __restrict__ cb,
                           const float* __restrict__ cc, float* __restrict__ out) {
  __shared__ float r_lds[BR][Dd];    // 32 KB residuals; reused as transpose buffer
  __shared__ float cb_lds[Kk][DC];   // 16 KB codebook D-chunk (XOR-swizzled 16B granules)
  __shared__ float cc_lds[Kk];       // 1 KB

  const int t  = threadIdx.x;
  const int tx = t & 31;   // code lane
  const int ty = t >> 5;   // row group 0..7
  const int brow = blockIdx.x * BR;

  // ---- load x tile into r_lds (coalesced float4) ----
  {
    const float4* xs = (const float4*)(x + (size_t)brow * Dd);
    float4* rd = (float4*)&r_lds[0][0];
#pragma unroll
    for (int i = 0; i < 8; ++i) rd[t + i * THREADS] = xs[t + i * THREADS];
  }
  __syncthreads();

  // ---- rr_reg[i] = ||r||^2 for this half-warp's 8 rows (common-mode term of d) ----
  float rr_reg[8];
#pragma unroll
  for (int i = 0; i < 8; ++i) {
    float4 v = *(const float4*)&r_lds[ty * 8 + i][tx * 4];
    float s = v.x * v.x;
    s = fmaf(v.y, v.y, s); s = fmaf(v.z, v.z, s); s = fmaf(v.w, v.w, s);
#pragma unroll
    for (int mask = 16; mask >= 1; mask >>= 1) s += __shfl_xor(s, mask, 64);
    rr_reg[i] = s;
  }

  for (int l = 0; l < Ll; ++l) {
    __syncthreads();                 // prev-level residual + cc/cb reuse fence
    cc_lds[t] = cc[l * Kk + t];

    float acc[8][8];
#pragma unroll
    for (int i = 0; i < 8; ++i)
#pragma unroll
      for (int j = 0; j < 8; ++j) acc[i][j] = 0.f;

    const float* cbl = cb + (size_t)l * Kk * Dd;

    for (int dc = 0; dc < Dd / DC; ++dc) {
      // ---- stage codebook D-chunk (swizzled) ----
      {
        const int k0 = t >> 2, dd4 = t & 3;
#pragma unroll
        for (int r = 0; r < 4; ++r) {
          int k = k0 + r * 64;
          float4 v = *(const float4*)(cbl + (size_t)k * Dd + dc * DC + dd4 * 4);
          int slot = dd4 ^ ((k >> 1) & 3);
          *(float4*)&cb_lds[k][slot * 4] = v;
        }
      }
      __syncthreads();
      // ---- GEMM: acc[i][j] += r[row_i] . cb[code_j], strictly ascending d,
      //      single-accumulator fmaf chain (matches BLAS/GPU k-sequential rounding) ----
#pragma unroll
      for (int dd4 = 0; dd4 < 4; ++dd4) {
        float4 rv[8], cv[8];
#pragma unroll
        for (int i = 0; i < 8; ++i)
          rv[i] = *(const float4*)&r_lds[ty * 8 + i][dc * DC + dd4 * 4];
#pragma unroll
        for (int j = 0; j < 8; ++j) {
          int code = tx + 32 * j;
          int slot = dd4 ^ ((code >> 1) & 3);
          cv[j] = *(const float4*)&cb_lds[code][slot * 4];
        }
#pragma unroll
        for (int i = 0; i < 8; ++i)
#pragma unroll
          for (int j = 0; j < 8; ++j) {
            acc[i][j] = fmaf(rv[i].x, cv[j].x, acc[i][j]);
            acc[i][j] = fmaf(rv[i].y, cv[j].y, acc[i][j]);
            acc[i][j] = fmaf(rv[i].z, cv[j].z, acc[i][j]);
            acc[i][j] = fmaf(rv[i].w, cv[j].w, acc[i][j]);
          }
      }
      __syncthreads();  // before next chunk overwrites cb_lds
    }

    // ---- per-row: argmin, softmax(probs), index, residual update, loss ----
#pragma unroll
    for (int i = 0; i < 8; ++i) {
      const int row = ty * 8 + i;
      // d = (rr - 2*s) + cc, mirroring the reference's evaluation/rounding order:
      // fmaf(-2,s,rr) == round(rr - 2s) (2s exact), then one more rounding for +cc.
      float d[8];
      float m = 1e30f; int mi = 0;
#pragma unroll
      for (int j = 0; j < 8; ++j) {
        int code = tx + 32 * j;
        d[j] = fmaf(-2.f, acc[i][j], rr_reg[i]) + cc_lds[code];
        if (d[j] < m) { m = d[j]; mi = code; }   // codes ascending in j -> first-min kept
      }
#pragma unroll
      for (int mask = 16; mask >= 1; mask >>= 1) {
        float om = __shfl_xor(m, mask, 64);
        int  omi = __shfl_xor(mi, mask, 64);
        if (om < m || (om == m && omi < mi)) { m = om; mi = omi; }
      }
      // softmax(-d) = exp(m - d)/sum  (m = min d)
      float p[8]; float ssum = 0.f;
#pragma unroll
      for (int j = 0; j < 8; ++j) { p[j] = __expf(m - d[j]); ssum += p[j]; }
#pragma unroll
      for (int mask = 16; mask >= 1; mask >>= 1) ssum += __shfl_xor(ssum, mask, 64);
      float inv = 1.f / ssum;

      // staged probs layout [B][L][K] (coalesced); transposed to [B][K][L] at the end
      size_t pbase = OUT_PROBS + (size_t)(brow + row) * (Kk * Ll) + (size_t)l * Kk;
#pragma unroll
      for (int j = 0; j < 8; ++j) out[pbase + tx + 32 * j] = p[j] * inv;

      if (tx == 0) out[OUT_IDX + (size_t)(brow + row) * Ll + l] = (float)mi;

      // residual update r -= cb[mi]; loss = 1.01 * ||r_new||^2 / 128
      float4 qv = *(const float4*)(cbl + (size_t)mi * Dd + tx * 4);
      float4 rv = *(float4*)&r_lds[row][tx * 4];
      rv.x -= qv.x; rv.y -= qv.y; rv.z -= qv.z; rv.w -= qv.w;
      *(float4*)&r_lds[row][tx * 4] = rv;
      float sq = rv.x * rv.x;
      sq = fmaf(rv.y, rv.y, sq); sq = fmaf(rv.z, rv.z, sq); sq = fmaf(rv.w, rv.w, sq);
#pragma unroll
      for (int mask = 16; mask >= 1; mask >>= 1) sq += __shfl_xor(sq, mask, 64);
      rr_reg[i] = sq;                 // ||r_new||^2 = next level's rr
      if (tx == 0)
        out[OUT_LOSS + (size_t)(brow + row) * Ll + l] = 1.01f * sq * (1.f / 128.f);
    }
  }

  // ---- quantized = x - r_final (coalesced) ----
  __syncthreads();
  {
    const float4* xs = (const float4*)(x + (size_t)brow * Dd);
    float4* outq = (float4*)(out + OUT_QUANT + (size_t)brow * Dd);
    const float4* rd = (const float4*)&r_lds[0][0];
#pragma unroll
    for (int i = 0; i < 8; ++i) {
      float4 xv = xs[t + i * THREADS];
      float4 rv = rd[t + i * THREADS];
      float4 q = { xv.x - rv.x, xv.y - rv.y, xv.z - rv.z, xv.w - rv.w };
      outq[t + i * THREADS] = q;
    }
  }

  // ---- in-place transpose of probs: [B][L][K] -> [B][K][L], 8 rows per pass ----
  float* tr = &r_lds[0][0];  // 8 rows * 1024 floats = 32 KB, reuse r_lds
  for (int g = 0; g < 8; ++g) {
    __syncthreads();  // guard r_lds reuse / previous pass
#pragma unroll
    for (int i = 0; i < 8; ++i) {
      int f4  = t + i * THREADS;  // 0..2047
      int row = f4 >> 8;          // 0..7 (256 float4 per row)
      int off = f4 & 255;
      float4 v = *(const float4*)&out[OUT_PROBS + (size_t)(brow + g * 8 + row) * 1024 + off * 4];
      *(float4*)&tr[row * 1024 + off * 4] = v;
    }
    __syncthreads();
#pragma unroll
    for (int i = 0; i < 8; ++i) {
      int task = t + i * THREADS;
      int row  = task >> 8;
      int k    = task & 255;
      float4 o = { tr[row * 1024 + 0 * 256 + k], tr[row * 1024 + 1 * 256 + k],
                   tr[row * 1024 + 2 * 256 + k], tr[row * 1024 + 3 * 256 + k] };
      *(float4*)&out[OUT_PROBS + (size_t)(brow + g * 8 + row) * 1024 + (size_t)k * 4] = o;
    }
  }
}

extern "C" void kernel_launch(void* const* d_in, const int* in_sizes, int n_in,
                              void* d_out, int out_size, void* d_ws, size_t ws_size,
                              hipStream_t stream) {
  const float* x  = (const float*)d_in[0];   // [B, D]
  const float* cb = (const float*)d_in[1];   // [L, K, D]
  float* out = (float*)d_out;
  float* cc  = (float*)d_ws;                 // L*K floats = 4 KB scratch

  cc_kernel<<<dim3((Ll * Kk) / 256), dim3(256), 0, stream>>>(cb, cc);
  rvq_kernel<<<dim3(Bq / BR), dim3(THREADS), 0, stream>>>(x, cb, cc, out);
}

// Round 6
// 813.106 us; speedup vs baseline: 1.0336x; 1.0336x over previous
//
#include <hip/hip_runtime.h>
#include <stdint.h>
#include <math.h>

// Residual VQ: x[B,D] fp32, codebooks[L,K,D] fp32
// Outputs (flat concat, fp32): hard_indices[B,L], soft_probs[B,K,L],
//                              quantized[B,D], quant_losses[B,L]
#define Bq 65536
#define Dd 128
#define Kk 256
#define Ll 4

constexpr int BR = 64;        // rows per block
constexpr int THREADS = 256;  // 32 tx (codes) x 8 ty (rows)
constexpr int DC = 16;        // D-chunk staged in LDS

constexpr size_t OUT_IDX   = 0;
constexpr size_t OUT_PROBS = (size_t)Bq * Ll;                 // 262144
constexpr size_t OUT_QUANT = OUT_PROBS + (size_t)Bq * Kk * Ll; // 67371008
constexpr size_t OUT_LOSS  = OUT_QUANT + (size_t)Bq * Dd;      // 75759616

// async global->LDS, 16B per lane; LDS dest = wave-uniform base + lane*16
__device__ __forceinline__ void gload_lds16(const float* g, float* l) {
  __builtin_amdgcn_global_load_lds(
      (const __attribute__((address_space(1))) unsigned int*)g,
      (__attribute__((address_space(3))) unsigned int*)l, 16, 0, 0);
}

// cc[l*K+k] = sum_d cb[l][k][d]^2  (1024 values)
__global__ void cc_kernel(const float* __restrict__ cb, float* __restrict__ cc) {
  int k = blockIdx.x * blockDim.x + threadIdx.x;  // 0..1023
  const float4* row = (const float4*)(cb + (size_t)k * Dd);
  float s = 0.f;
#pragma unroll
  for (int i = 0; i < Dd / 4; ++i) {
    float4 v = row[i];
    s += v.x * v.x + v.y * v.y + v.z * v.z + v.w * v.w;
  }
  cc[k] = s;
}

__launch_bounds__(THREADS)
__global__ void rvq_kernel(const float* __restrict__ x, const float* __restrict__ cb,
                           const float* __restrict__ cc, float* __restrict__ out) {
  __shared__ float r_lds[BR][Dd];        // 32 KB residuals
  __shared__ float cb_lds[2][Kk][DC];    // 2 x 16 KB codebook chunk, double-buffered
  __shared__ float cc_lds[Kk];           // 1 KB

  const int t    = threadIdx.x;
  const int tx   = t & 31;   // code lane
  const int ty   = t >> 5;   // row group 0..7
  const int wv   = t >> 6;   // wave 0..3
  const int lane = t & 63;
  const int brow = blockIdx.x * BR;

  // ---- load x tile into r_lds (coalesced float4) ----
  {
    const float4* xs = (const float4*)(x + (size_t)brow * Dd);
    float4* rd = (float4*)&r_lds[0][0];
#pragma unroll
    for (int i = 0; i < 8; ++i) rd[t + i * THREADS] = xs[t + i * THREADS];
  }
  __syncthreads();

  // ---- rr_reg[i] = ||r||^2 for this half-wave's 8 rows (common-mode term of d) ----
  float rr_reg[8];
#pragma unroll
  for (int i = 0; i < 8; ++i) {
    float4 v = *(const float4*)&r_lds[ty * 8 + i][tx * 4];
    float s = v.x * v.x;
    s = fmaf(v.y, v.y, s); s = fmaf(v.z, v.z, s); s = fmaf(v.w, v.w, s);
#pragma unroll
    for (int mask = 16; mask >= 1; mask >>= 1) s += __shfl_xor(s, mask, 64);
    rr_reg[i] = s;
  }

  for (int l = 0; l < Ll; ++l) {
    const float* cbl = cb + (size_t)l * Kk * Dd;

    // stage chunk dc into cb_lds[b]: 4 waves x 4 x 1KB gload_lds.
    // LDS is linear [k][slot]; the XOR swizzle slot = dd4 ^ ((k>>1)&3) is applied by
    // PRE-SWIZZLING the per-lane GLOBAL source address (G21: gload_lds dest is linear).
    auto stage = [&](int b, int dc) {
#pragma unroll
      for (int q = 0; q < 4; ++q) {
        int region = wv * 4 + q;              // wave-uniform 0..15 (1KB each)
        int k      = region * 16 + (lane >> 2);
        int slot   = lane & 3;
        int dd4s   = slot ^ ((k >> 1) & 3);
        const float* g = cbl + (size_t)k * Dd + dc * DC + dd4s * 4;
        gload_lds16(g, &cb_lds[b][0][0] + region * 256);  // uniform base
      }
    };

    cc_lds[t] = cc[l * Kk + t];
    stage(0, 0);
    __syncthreads();   // drains stage(0) vmcnt + prev epilogue r_lds + cc_lds

    float acc[8][8];
#pragma unroll
    for (int i = 0; i < 8; ++i)
#pragma unroll
      for (int j = 0; j < 8; ++j) acc[i][j] = 0.f;

    for (int dc = 0; dc < Dd / DC; ++dc) {
      if (dc < Dd / DC - 1) stage((dc + 1) & 1, dc + 1);  // prefetch next chunk
      const int b = dc & 1;
      // ---- GEMM: acc[i][j] += r[row_i] . cb[code_j], strictly ascending d,
      //      single-accumulator fmaf chain (matches BLAS/GPU k-sequential rounding) ----
#pragma unroll
      for (int dd4 = 0; dd4 < 4; ++dd4) {
        float4 rv[8], cv[8];
#pragma unroll
        for (int i = 0; i < 8; ++i)
          rv[i] = *(const float4*)&r_lds[ty * 8 + i][dc * DC + dd4 * 4];
#pragma unroll
        for (int j = 0; j < 8; ++j) {
          int code = tx + 32 * j;
          int slot = dd4 ^ ((code >> 1) & 3);
          cv[j] = *(const float4*)&cb_lds[b][code][slot * 4];
        }
#pragma unroll
        for (int i = 0; i < 8; ++i)
#pragma unroll
          for (int j = 0; j < 8; ++j) {
            acc[i][j] = fmaf(rv[i].x, cv[j].x, acc[i][j]);
            acc[i][j] = fmaf(rv[i].y, cv[j].y, acc[i][j]);
            acc[i][j] = fmaf(rv[i].z, cv[j].z, acc[i][j]);
            acc[i][j] = fmaf(rv[i].w, cv[j].w, acc[i][j]);
          }
      }
      __syncthreads();  // next-chunk staging complete (vmcnt) + buffer handoff
    }

    // ---- per-row: argmin, softmax(probs), index, residual update, loss ----
#pragma unroll
    for (int i = 0; i < 8; ++i) {
      const int row = ty * 8 + i;
      // d = (rr - 2*s) + cc, mirroring the reference's evaluation/rounding order:
      // fmaf(-2,s,rr) == round(rr - 2s) (2s exact), then one more rounding for +cc.
      float d[8];
      float m = 1e30f; int mi = 0;
#pragma unroll
      for (int j = 0; j < 8; ++j) {
        int code = tx + 32 * j;
        d[j] = fmaf(-2.f, acc[i][j], rr_reg[i]) + cc_lds[code];
        if (d[j] < m) { m = d[j]; mi = code; }   // codes ascending in j -> first-min kept
      }
#pragma unroll
      for (int mask = 16; mask >= 1; mask >>= 1) {
        float om = __shfl_xor(m, mask, 64);
        int  omi = __shfl_xor(mi, mask, 64);
        if (om < m || (om == m && omi < mi)) { m = om; mi = omi; }
      }
      // softmax(-d) = exp(m - d)/sum  (m = min d)
      float p[8]; float ssum = 0.f;
#pragma unroll
      for (int j = 0; j < 8; ++j) { p[j] = __expf(m - d[j]); ssum += p[j]; }
#pragma unroll
      for (int mask = 16; mask >= 1; mask >>= 1) ssum += __shfl_xor(ssum, mask, 64);
      float inv = 1.f / ssum;

      // staged probs layout [B][L][K] (coalesced); transposed by tr_kernel afterwards
      size_t pbase = OUT_PROBS + (size_t)(brow + row) * (Kk * Ll) + (size_t)l * Kk;
#pragma unroll
      for (int j = 0; j < 8; ++j) out[pbase + tx + 32 * j] = p[j] * inv;

      if (tx == 0) out[OUT_IDX + (size_t)(brow + row) * Ll + l] = (float)mi;

      // residual update r -= cb[mi]; loss = 1.01 * ||r_new||^2 / 128
      float4 qv = *(const float4*)(cbl + (size_t)mi * Dd + tx * 4);
      float4 rv = *(float4*)&r_lds[row][tx * 4];
      rv.x -= qv.x; rv.y -= qv.y; rv.z -= qv.z; rv.w -= qv.w;
      *(float4*)&r_lds[row][tx * 4] = rv;
      float sq = rv.x * rv.x;
      sq = fmaf(rv.y, rv.y, sq); sq = fmaf(rv.z, rv.z, sq); sq = fmaf(rv.w, rv.w, sq);
#pragma unroll
      for (int mask = 16; mask >= 1; mask >>= 1) sq += __shfl_xor(sq, mask, 64);
      rr_reg[i] = sq;                 // ||r_new||^2 = next level's rr
      if (tx == 0)
        out[OUT_LOSS + (size_t)(brow + row) * Ll + l] = 1.01f * sq * (1.f / 128.f);
    }
  }

  // ---- quantized = x - r_final (coalesced) ----
  __syncthreads();
  {
    const float4* xs = (const float4*)(x + (size_t)brow * Dd);
    float4* outq = (float4*)(out + OUT_QUANT + (size_t)brow * Dd);
    const float4* rd = (const float4*)&r_lds[0][0];
#pragma unroll
    for (int i = 0; i < 8; ++i) {
      float4 xv = xs[t + i * THREADS];
      float4 rv = rd[t + i * THREADS];
      float4 q = { xv.x - rv.x, xv.y - rv.y, xv.z - rv.z, xv.w - rv.w };
      outq[t + i * THREADS] = q;
    }
  }
}

// in-place transpose of probs rows: [b][L][K] -> [b][K][L], 64 rows per block
__launch_bounds__(THREADS)
__global__ void tr_kernel(float* __restrict__ out) {
  __shared__ float tr[8 * 1024];  // 32 KB -> 5 blocks/CU
  const int t = threadIdx.x;
  const size_t brow = (size_t)blockIdx.x * BR;
  for (int g = 0; g < 8; ++g) {
    if (g) __syncthreads();  // guard tr reuse from previous pass
#pragma unroll
    for (int i = 0; i < 8; ++i) {
      int f4  = t + i * THREADS;  // 0..2047
      int row = f4 >> 8;          // 0..7 (256 float4 per row)
      int off = f4 & 255;
      float4 v = *(const float4*)&out[OUT_PROBS + (brow + g * 8 + row) * 1024 + off * 4];
      *(float4*)&tr[row * 1024 + off * 4] = v;
    }
    __syncthreads();
#pragma unroll
    for (int i = 0; i < 8; ++i) {
      int task = t + i * THREADS;
      int row  = task >> 8;
      int k    = task & 255;
      float4 o = { tr[row * 1024 + 0 * 256 + k], tr[row * 1024 + 1 * 256 + k],
                   tr[row * 1024 + 2 * 256 + k], tr[row * 1024 + 3 * 256 + k] };
      *(float4*)&out[OUT_PROBS + (brow + g * 8 + row) * 1024 + (size_t)k * 4] = o;
    }
  }
}

extern "C" void kernel_launch(void* const* d_in, const int* in_sizes, int n_in,
                              void* d_out, int out_size, void* d_ws, size_t ws_size,
                              hipStream_t stream) {
  const float* x  = (const float*)d_in[0];   // [B, D]
  const float* cb = (const float*)d_in[1];   // [L, K, D]
  float* out = (float*)d_out;
  float* cc  = (float*)d_ws;                 // L*K floats = 4 KB scratch

  cc_kernel<<<dim3((Ll * Kk) / 256), dim3(256), 0, stream>>>(cb, cc);
  rvq_kernel<<<dim3(Bq / BR), dim3(THREADS), 0, stream>>>(x, cb, cc, out);
  tr_kernel<<<dim3(Bq / BR), dim3(THREADS), 0, stream>>>(out);
}